// Round 10
// baseline (36.172 us; speedup 1.0000x reference)
//
#include <hip/hip_runtime.h>
#include <stdint.h>

constexpr int NTOK = 262144;
constexpr int D    = 64;   // CODE_DIM
constexpr int K    = 16;   // NUM_CODES
constexpr int TPB  = 256;
constexpr int ROW4 = D / 4;          // 16 float4 per token row
constexpr int TOKB = 64;             // tokens per block (4 threads/token)

// Direct global->LDS 16B async copy (gfx950). LDS dest = wave-uniform base + lane*16.
__device__ __forceinline__ void gload_lds16(const float4* gsrc, float4* ldst) {
    __builtin_amdgcn_global_load_lds(
        (const __attribute__((address_space(1))) uint32_t*)gsrc,
        (__attribute__((address_space(3))) uint32_t*)ldst, 16, 0, 0);
}

__global__ __launch_bounds__(TPB, 8) void quantizer_kernel(
    const float* __restrict__ x, const float* __restrict__ cb, float* __restrict__ out)
{
    // 16 KiB slab. Logical [token][col4] at phys token*16 + (col ^ (token&15)).
    // Filled by global_load_lds with PRE-SWIZZLED SOURCE (linear dest, rule #21):
    // slot s holds X[(s&~15) | ((s&15)^((s>>4)&15))]  -- XOR involution within 256B rows.
    __shared__ float4 slab[TOKB * ROW4];

    const int tid = threadIdx.x;
    const int ln  = tid & 63;                                   // token within block
    const int w   = __builtin_amdgcn_readfirstlane(tid >> 6);   // wave id = quarter (SGPR)

    const float4* __restrict__ X4  = reinterpret_cast<const float4*>(x);
    const float4* __restrict__ CB4 = reinterpret_cast<const float4*>(cb);
    float4* __restrict__ out4      = reinterpret_cast<float4*>(out);

    const size_t blk4 = (size_t)blockIdx.x * TOKB * ROW4;

    // ---- Phase 0: async global->LDS, 1 KiB/wave/instr. Lane ln of wave w, iter it
    //      fills slot s = it*256 + w*64 + ln; source element g(s) applies the XOR swizzle.
    //      Same 16 fully-covered 64B lines per instr as linear -> coalescing preserved. ----
#pragma unroll
    for (int it = 0; it < 4; ++it) {
        const int s = it * 256 + w * 64 + ln;                // slot this lane fills
        const int g = (s & ~15) | ((s & 15) ^ ((s >> 4) & 15));
        gload_lds16(X4 + blk4 + g, &slab[it * 256 + w * 64]); // dest: wave-uniform base
    }
    __syncthreads();   // barrier 1 (drains vmcnt)

    // ---- Phase 1: own token's quarter from LDS (conflict-free under swizzle) ----
    float4 xr[4];
#pragma unroll
    for (int j = 0; j < 4; ++j)
        xr[j] = slab[(ln << 4) + ((w * 4 + j) ^ (ln & 15))];

    // ---- Phase 2: 16 partials — f32 fmaf chain per 16-elem quarter, BIT-IDENTICAL
    //      to proven R5/R8/R9 inner block. Overwrite the SAME slots this wave just
    //      consumed (per-wave disjoint -> no barrier needed between 1 and 2). ----
#pragma unroll
    for (int q = 0; q < 4; ++q) {
        float pq[4];
#pragma unroll
        for (int c = 0; c < 4; ++c) {
            const int k = 4 * q + c;
            float pp = 0.f;
#pragma unroll
            for (int j = 0; j < 4; ++j) {
                float4 cc = CB4[k * ROW4 + w * 4 + j];   // SGPR-uniform -> s_load, K$-hot
                float4 xv = xr[j];
                float d0 = xv.x - cc.x, d1 = xv.y - cc.y;
                float d2 = xv.z - cc.z, d3 = xv.w - cc.w;
                pp = fmaf(d0, d0, pp);
                pp = fmaf(d1, d1, pp);
                pp = fmaf(d2, d2, pp);
                pp = fmaf(d3, d3, pp);
            }
            pq[c] = pp;
        }
        slab[(ln << 4) + ((w * 4 + q) ^ (ln & 15))] =
            make_float4(pq[0], pq[1], pq[2], pq[3]);
    }
    __syncthreads();   // barrier 2

    // ---- Phase 3: combine in f64, quarter order 0,1,2,3 == proven b-order;
    //      strict-< first-occurrence argmin, k ascending. ----
    double best = 1e300;
    int bidx = 0;
#pragma unroll
    for (int q = 0; q < 4; ++q) {
        float4 f0 = slab[(ln << 4) + ((0 * 4 + q) ^ (ln & 15))];
        float4 f1 = slab[(ln << 4) + ((1 * 4 + q) ^ (ln & 15))];
        float4 f2 = slab[(ln << 4) + ((2 * 4 + q) ^ (ln & 15))];
        float4 f3 = slab[(ln << 4) + ((3 * 4 + q) ^ (ln & 15))];
#define COMB(CMP, KK)                                                       \
        { double a = (double)f0.CMP; a += f1.CMP; a += f2.CMP; a += f3.CMP; \
          if (a < best) { best = a; bidx = 4 * q + KK; } }
        COMB(x, 0) COMB(y, 1) COMB(z, 2) COMB(w, 3)
#undef COMB
    }

    // ---- onehot: one coalesced float4 per thread (block region = 4 KiB) ----
    {
        const int tok = tid >> 2;                 // token in block [0,64)
        const int b   = __shfl(bidx, tok);        // identical across waves
        const int sub = tid & 3;
        float4 v;
        v.x = (b == sub * 4 + 0) ? 1.f : 0.f;
        v.y = (b == sub * 4 + 1) ? 1.f : 0.f;
        v.z = (b == sub * 4 + 2) ? 1.f : 0.f;
        v.w = (b == sub * 4 + 3) ? 1.f : 0.f;
        out4[(size_t)blockIdx.x * (TOKB * K / 4) + tid] = v;
    }

    // ---- residual: coalesced L2-hot re-read of x (same block's lines, 64KB/block),
    //      per-lane codebook gather (4 KiB, L1-resident), coalesced stores ----
    const size_t rbase = (size_t)NTOK * (K / 4) + blk4;
#pragma unroll
    for (int it = 0; it < 4; ++it) {
        const int i   = it * TPB + tid;
        const int tok = i >> 4;
        const int b   = __shfl(bidx, tok);
        float4 c  = CB4[b * ROW4 + (tid & 15)];
        float4 xv = X4[blk4 + i];
        float4 r;
        r.x = xv.x - c.x; r.y = xv.y - c.y;
        r.z = xv.z - c.z; r.w = xv.w - c.w;
        out4[rbase + i] = r;
    }
}

extern "C" void kernel_launch(void* const* d_in, const int* in_sizes, int n_in,
                              void* d_out, int out_size, void* d_ws, size_t ws_size,
                              hipStream_t stream) {
    const float* x  = (const float*)d_in[0];   // [262144, 64] fp32
    const float* cb = (const float*)d_in[1];   // [16, 64] fp32
    float* out = (float*)d_out;                // [N*16 onehot | N*64 residual] fp32

    quantizer_kernel<<<NTOK / TOKB, TPB, 0, stream>>>(x, cb, out);
}

// Round 12
// 30.624 us; speedup vs baseline: 1.1812x; 1.1812x over previous
//
#include <hip/hip_runtime.h>

constexpr int NTOK = 262144;
constexpr int D    = 64;   // CODE_DIM
constexpr int K    = 16;   // NUM_CODES
constexpr int TPB  = 256;
constexpr int ROW4 = D / 4;          // 16 float4 per token row
constexpr int TOKB = 64;             // tokens per block (4 threads/token)

typedef float v2f __attribute__((ext_vector_type(2)));
typedef float v4f __attribute__((ext_vector_type(4)));   // native vec: OK for nontemporal builtins

__global__ __launch_bounds__(TPB, 8) void quantizer_kernel(
    const float* __restrict__ x, const float* __restrict__ cb, float* __restrict__ out)
{
    // 16 KiB slab, reused: x-transpose, then distance partials.
    // Logical [token][col4] at phys token*16 + (col ^ (token&15))  (v4f units).
    __shared__ v4f slab[TOKB * ROW4];

    const int tid = threadIdx.x;
    const int ln  = tid & 63;                                   // token within block
    const int w   = __builtin_amdgcn_readfirstlane(tid >> 6);   // wave id = quarter (SGPR)

    const v4f* __restrict__ X4  = reinterpret_cast<const v4f*>(x);
    const v4f* __restrict__ CB4 = reinterpret_cast<const v4f*>(cb);
    v4f* __restrict__ out4      = reinterpret_cast<v4f*>(out);

    const size_t blk4 = (size_t)blockIdx.x * TOKB * ROW4;

    // ---- Phase 0: the ONLY global read of x — fully coalesced, non-temporal
    //      (read-once stream; don't pollute L2). Keep in regs for residual phase;
    //      also stage into swizzled slab. ----
    v4f xs[4];
#pragma unroll
    for (int it = 0; it < 4; ++it) {
        const int i = it * TPB + tid;
        xs[it] = __builtin_nontemporal_load(&X4[blk4 + i]);
        const int t = i >> 4, c = i & 15;
        slab[(t << 4) + (c ^ (t & 15))] = xs[it];   // conflict-free (8/bank-group)
    }
    __syncthreads();   // barrier 1

    // ---- Phase 1: own token's quarter from LDS (wave w touches ONLY cols w*4..w*4+3) ----
    v4f xr[4];
#pragma unroll
    for (int j = 0; j < 4; ++j)
        xr[j] = slab[(ln << 4) + ((w * 4 + j) ^ (ln & 15))];

    // ---- Phase 2: 16 partials per 16-elem quarter — PACKED f32 (v_pk_fma_f32):
    //      two 8-term chains (even/odd lanes) + one f32 combine. Reassociation of
    //      the proven R9 chain; error same order (~n*eps), residual exact. ----
#pragma unroll
    for (int q = 0; q < 4; ++q) {
        float pq[4];
#pragma unroll
        for (int c = 0; c < 4; ++c) {
            const int k = 4 * q + c;
            v2f pp = {0.f, 0.f};
#pragma unroll
            for (int j = 0; j < 4; ++j) {
                v4f cc = CB4[k * ROW4 + w * 4 + j];   // SGPR-uniform -> s_load, K$-hot
                v4f xv = xr[j];
                v2f xlo = {xv.x, xv.y}, xhi = {xv.z, xv.w};
                v2f clo = {cc.x, cc.y}, chi = {cc.z, cc.w};
                v2f dlo = xlo - clo;
                pp = __builtin_elementwise_fma(dlo, dlo, pp);
                v2f dhi = xhi - chi;
                pp = __builtin_elementwise_fma(dhi, dhi, pp);
            }
            pq[c] = pp.x + pp.y;
        }
        // overwrite the SAME slots this wave just consumed (per-wave disjoint: no barrier)
        slab[(ln << 4) + ((w * 4 + q) ^ (ln & 15))] = (v4f){pq[0], pq[1], pq[2], pq[3]};
    }
    __syncthreads();   // barrier 2

    // ---- Phase 3: combine in f64, quarter order 0,1,2,3; strict-< first-occurrence
    //      argmin, k ascending (same decision procedure as proven rounds). ----
    double best = 1e300;
    int bidx = 0;
#pragma unroll
    for (int q = 0; q < 4; ++q) {
        v4f f0 = slab[(ln << 4) + ((0 * 4 + q) ^ (ln & 15))];
        v4f f1 = slab[(ln << 4) + ((1 * 4 + q) ^ (ln & 15))];
        v4f f2 = slab[(ln << 4) + ((2 * 4 + q) ^ (ln & 15))];
        v4f f3 = slab[(ln << 4) + ((3 * 4 + q) ^ (ln & 15))];
#define COMB(CMP, KK)                                                       \
        { double a = (double)f0.CMP; a += f1.CMP; a += f2.CMP; a += f3.CMP; \
          if (a < best) { best = a; bidx = 4 * q + KK; } }
        COMB(x, 0) COMB(y, 1) COMB(z, 2) COMB(w, 3)
#undef COMB
    }

    // ---- onehot: one coalesced non-temporal v4f per thread ----
    {
        const int tok = tid >> 2;                 // token in block [0,64)
        const int b   = __shfl(bidx, tok);        // identical across waves
        const int sub = tid & 3;
        v4f v;
        v.x = (b == sub * 4 + 0) ? 1.f : 0.f;
        v.y = (b == sub * 4 + 1) ? 1.f : 0.f;
        v.z = (b == sub * 4 + 2) ? 1.f : 0.f;
        v.w = (b == sub * 4 + 3) ? 1.f : 0.f;
        __builtin_nontemporal_store(v, &out4[(size_t)blockIdx.x * (TOKB * K / 4) + tid]);
    }

    // ---- residual: from xs regs (x read ONCE from HBM — the R10 lesson),
    //      per-lane codebook gather (4 KiB L1-resident), non-temporal stores ----
    const size_t rbase = (size_t)NTOK * (K / 4) + blk4;
#pragma unroll
    for (int it = 0; it < 4; ++it) {
        const int i   = it * TPB + tid;
        const int tok = i >> 4;
        const int b   = __shfl(bidx, tok);
        v4f c  = CB4[b * ROW4 + (tid & 15)];
        v4f xv = xs[it];
        v4f r  = xv - c;
        __builtin_nontemporal_store(r, &out4[rbase + i]);
    }
}

extern "C" void kernel_launch(void* const* d_in, const int* in_sizes, int n_in,
                              void* d_out, int out_size, void* d_ws, size_t ws_size,
                              hipStream_t stream) {
    const float* x  = (const float*)d_in[0];   // [262144, 64] fp32
    const float* cb = (const float*)d_in[1];   // [16, 64] fp32
    float* out = (float*)d_out;                // [N*16 onehot | N*64 residual] fp32

    quantizer_kernel<<<NTOK / TOKB, TPB, 0, stream>>>(x, cb, out);
}

// Round 13
// 28.868 us; speedup vs baseline: 1.2530x; 1.0608x over previous
//
#include <hip/hip_runtime.h>

constexpr int NTOK = 262144;
constexpr int D    = 64;   // CODE_DIM
constexpr int K    = 16;   // NUM_CODES
constexpr int TPB  = 256;
constexpr int ROW4 = D / 4;          // 16 float4 per token row
constexpr int TOKB = 64;             // tokens per block (4 threads/token)

__global__ __launch_bounds__(TPB, 8) void quantizer_kernel(
    const float* __restrict__ x, const float* __restrict__ cb, float* __restrict__ out)
{
    // 16 KiB slab, reused: x-transpose, then distance partials.
    // Logical [token][col4] at phys token*16 + (col ^ (token&15))  (float4 units).
    __shared__ float4 slab[TOKB * ROW4];

    const int tid = threadIdx.x;
    const int ln  = tid & 63;                                   // token within block
    const int w   = __builtin_amdgcn_readfirstlane(tid >> 6);   // wave id = quarter (SGPR)

    const float4* __restrict__ X4  = reinterpret_cast<const float4*>(x);
    const float4* __restrict__ CB4 = reinterpret_cast<const float4*>(cb);
    float4* __restrict__ out4      = reinterpret_cast<float4*>(out);

    const size_t blk4 = (size_t)blockIdx.x * TOKB * ROW4;

    // ---- Phase 0: the ONLY global read of x — fully coalesced (1 KiB/wave/instr).
    //      Keep in regs for the residual phase; also stage into swizzled slab. ----
    float4 xs[4];
#pragma unroll
    for (int it = 0; it < 4; ++it) {
        const int i = it * TPB + tid;
        xs[it] = X4[blk4 + i];
        const int t = i >> 4, c = i & 15;
        slab[(t << 4) + (c ^ (t & 15))] = xs[it];   // conflict-free (8/bank-group)
    }
    __syncthreads();   // barrier 1

    // ---- Phase 1: own token's quarter from LDS (wave w touches ONLY cols w*4..w*4+3) ----
    float4 xr[4];
#pragma unroll
    for (int j = 0; j < 4; ++j)
        xr[j] = slab[(ln << 4) + ((w * 4 + j) ^ (ln & 15))];

    // ---- Phase 2: 16 partials — f32 fmaf chain per 16-elem quarter, BIT-IDENTICAL
    //      to proven R5/R8 inner block. Write back into the SAME slots this wave
    //      just consumed (per-wave disjoint -> no barrier needed here). ----
#pragma unroll
    for (int q = 0; q < 4; ++q) {
        float pq[4];
#pragma unroll
        for (int c = 0; c < 4; ++c) {
            const int k = 4 * q + c;
            float pp = 0.f;
#pragma unroll
            for (int j = 0; j < 4; ++j) {
                float4 cc = CB4[k * ROW4 + w * 4 + j];   // SGPR-uniform -> s_load, K$-hot
                float4 xv = xr[j];
                float d0 = xv.x - cc.x, d1 = xv.y - cc.y;
                float d2 = xv.z - cc.z, d3 = xv.w - cc.w;
                pp = fmaf(d0, d0, pp);
                pp = fmaf(d1, d1, pp);
                pp = fmaf(d2, d2, pp);
                pp = fmaf(d3, d3, pp);
            }
            pq[c] = pp;
        }
        slab[(ln << 4) + ((w * 4 + q) ^ (ln & 15))] =
            make_float4(pq[0], pq[1], pq[2], pq[3]);
    }
    __syncthreads();   // barrier 2

    // ---- Phase 3: combine partials in f64, quarter order 0,1,2,3 == proven b-order;
    //      strict-< first-occurrence argmin, k ascending. ----
    double best = 1e300;
    int bidx = 0;
#pragma unroll
    for (int q = 0; q < 4; ++q) {
        float4 f0 = slab[(ln << 4) + ((0 * 4 + q) ^ (ln & 15))];
        float4 f1 = slab[(ln << 4) + ((1 * 4 + q) ^ (ln & 15))];
        float4 f2 = slab[(ln << 4) + ((2 * 4 + q) ^ (ln & 15))];
        float4 f3 = slab[(ln << 4) + ((3 * 4 + q) ^ (ln & 15))];
#define COMB(CMP, KK)                                                       \
        { double a = (double)f0.CMP; a += f1.CMP; a += f2.CMP; a += f3.CMP; \
          if (a < best) { best = a; bidx = 4 * q + KK; } }
        COMB(x, 0) COMB(y, 1) COMB(z, 2) COMB(w, 3)
#undef COMB
    }

    // ---- onehot: one coalesced float4 per thread (block region = 4 KiB) ----
    {
        const int tok = tid >> 2;                 // token in block [0,64)
        const int b   = __shfl(bidx, tok);        // identical across waves
        const int sub = tid & 3;
        float4 v;
        v.x = (b == sub * 4 + 0) ? 1.f : 0.f;
        v.y = (b == sub * 4 + 1) ? 1.f : 0.f;
        v.z = (b == sub * 4 + 2) ? 1.f : 0.f;
        v.w = (b == sub * 4 + 3) ? 1.f : 0.f;
        out4[(size_t)blockIdx.x * (TOKB * K / 4) + tid] = v;
    }

    // ---- residual: from xs regs (x read ONCE from HBM), coalesced stores ----
    const size_t rbase = (size_t)NTOK * (K / 4) + blk4;
#pragma unroll
    for (int it = 0; it < 4; ++it) {
        const int i   = it * TPB + tid;
        const int tok = i >> 4;
        const int b   = __shfl(bidx, tok);
        float4 c  = CB4[b * ROW4 + (tid & 15)];   // per-lane b, 4 KiB L1-resident
        float4 xv = xs[it];
        float4 r;
        r.x = xv.x - c.x; r.y = xv.y - c.y;
        r.z = xv.z - c.z; r.w = xv.w - c.w;
        out4[rbase + i] = r;
    }
}

extern "C" void kernel_launch(void* const* d_in, const int* in_sizes, int n_in,
                              void* d_out, int out_size, void* d_ws, size_t ws_size,
                              hipStream_t stream) {
    const float* x  = (const float*)d_in[0];   // [262144, 64] fp32
    const float* cb = (const float*)d_in[1];   // [16, 64] fp32
    float* out = (float*)d_out;                // [N*16 onehot | N*64 residual] fp32

    quantizer_kernel<<<NTOK / TOKB, TPB, 0, stream>>>(x, cb, out);
}